// Round 12
// baseline (94.563 us; speedup 1.0000x reference)
//
#include <hip/hip_runtime.h>

#define NQ 10
#define TS 10
#define DIM 1024
#define ND 1024
#define NR 16    // 16 complex amplitudes per lane (Sr/Si float arrays)

// Circuit algebra (R9-verified): M = Rz(b)·Ry(th)·Rz(a); per-qubit factors
// commute, so each step = [Pi Rz(b)]·[Pi Ry]·[Pi Rz(a)]·D_pair and all
// diagonals merge across step boundaries into ONE diagonal per boundary:
//   phi(idx) = sum_{set bits} v_i - 0.5*sum(v) + k*pairsum(idx),
//   v_i = a_i(t) + b_i(t-1) (b(-1)=0), k = -0.5*theta(t-1) (0 at t=0).
// Ry is a REAL Givens rotation: 2 ops per float per gate.
// R11: software-pipelined uniform phi loads (prefetch next step during current).

// ---------- full-rate cross-lane exchange via DPP (verified R5) ----------
template<int CTRL>
__device__ __forceinline__ float dpp_full(float x) {
    const int xi = __float_as_int(x);
    return __int_as_float(__builtin_amdgcn_update_dpp(xi, xi, CTRL, 0xF, 0xF, false));
}
__device__ __forceinline__ float dpp_xor4(float x) {
    const int xi = __float_as_int(x);
    // banks 0,2 (bit2=0) need src[i+4] -> row_shl:4 (0x104), bank_mask 0x5
    // banks 1,3 (bit2=1) need src[i-4] -> row_shr:4 (0x114), bank_mask 0xA
    int q = __builtin_amdgcn_update_dpp(0, xi, 0x104, 0xF, 0x5, false);
    q     = __builtin_amdgcn_update_dpp(q, xi, 0x114, 0xF, 0xA, false);
    return __int_as_float(q);
}
__device__ __forceinline__ float bperm(int addr, float x) {  // addr hoisted
    return __int_as_float(__builtin_amdgcn_ds_bpermute(addr, __float_as_int(x)));
}
template<int MASK>
__device__ __forceinline__ float lshuf(float x, int addr) {
    if constexpr (MASK == 1)      return dpp_full<0xB1>(x);   // quad_perm [1,0,3,2]
    else if constexpr (MASK == 2) return dpp_full<0x4E>(x);   // quad_perm [2,3,0,1]
    else if constexpr (MASK == 4) return dpp_xor4(x);
    else if constexpr (MASK == 8) return dpp_full<0x128>(x);  // row_ror:8 == xor8
    else return bperm(addr, x);                               // 16,32
}

// ---------- Ry gates (real rotation [[c,-s],[s,c]]) ----------
template <int RB>   // pairing on register bit RB
__device__ __forceinline__ void ry_r(float* Sr, float* Si, float c, float s) {
#pragma unroll
    for (int r0 = 0; r0 < NR; ++r0) {
        if (r0 & (1 << RB)) continue;
        const int r1 = r0 | (1 << RB);
        const float x0r = Sr[r0], x1r = Sr[r1];
        const float x0i = Si[r0], x1i = Si[r1];
        Sr[r0] = c * x0r - s * x1r;
        Sr[r1] = s * x0r + c * x1r;
        Si[r0] = c * x0i - s * x1i;
        Si[r1] = s * x0i + c * x1i;
    }
}
template <int MASK> // pairing on lane bit MASK
__device__ __forceinline__ void ry_lane(int lane, int addr, float* Sr, float* Si,
                                        float c, float s) {
    const float ss = (lane & MASK) ? s : -s;  // x' = c*own + ss*partner
    float qr[NR], qi[NR];
#pragma unroll
    for (int r = 0; r < NR; ++r) {
        qr[r] = lshuf<MASK>(Sr[r], addr);
        qi[r] = lshuf<MASK>(Si[r], addr);
    }
#pragma unroll
    for (int r = 0; r < NR; ++r) {
        Sr[r] = c * Sr[r] + ss * qr[r];
        Si[r] = c * Si[r] + ss * qi[r];
    }
}

// One wave per sample, full state in registers, zero LDS.
__global__ __launch_bounds__(64, 1) void qsim_kernel(
    const float* __restrict__ re_in, const float* __restrict__ im_in,
    const float* __restrict__ phis, const float* __restrict__ gs,
    float* __restrict__ out)
{
    const int sample = blockIdx.x;
    const int lane = threadIdx.x;

    const float* pr_in = re_in + sample * DIM;
    const float* pi_in = im_in + sample * DIM;
    const float* ph = phis + sample * (3 * NQ * TS);
    const float* gsp = gs + sample * TS;

    // ---- issue first-step uniform loads + gs immediately (longest latency) ----
    float phs[30];
#pragma unroll
    for (int j = 0; j < 30; ++j) phs[j] = ph[j];

    const float inv = 0.15811388300841897f;  // 1/(2*sqrt(10))
    float gk[TS];                             // -0.5 * theta(t), preloaded
#pragma unroll
    for (int t = 0; t < TS; ++t) gk[t] = -0.5f * (gsp[t] * inv);

    float Sr[NR], Si[NR];
#pragma unroll
    for (int r = 0; r < NR; ++r) {
        Sr[r] = pr_in[r * 64 + lane];
        Si[r] = pi_in[r * 64 + lane];
    }

    const int bp16 = (lane ^ 16) << 2;   // hoisted bpermute byte-addresses
    const int bp32 = (lane ^ 32) << 2;

    // ---- normalize ----
    float nrm = 0.f;
#pragma unroll
    for (int r = 0; r < NR; ++r) nrm += Sr[r] * Sr[r] + Si[r] * Si[r];
#pragma unroll
    for (int off = 32; off >= 1; off >>= 1) nrm += __shfl_xor(nrm, off, 64);
    const float scl = rsqrtf(nrm);
#pragma unroll
    for (int r = 0; r < NR; ++r) { Sr[r] *= scl; Si[r] *= scl; }

    // ---- static per-amp pairsum ----
    float ps[NR];
#pragma unroll
    for (int r = 0; r < NR; ++r) {
        const int idx = r * 64 + lane;
        const int z = NQ - 2 * __popc(idx);
        ps[r] = 0.5f * (float)(z * z - NQ);
    }
    // lane-bit indicators for qubits 4..9 (qubit 4+j <-> lane bit 5-j)
    float bl[6];
#pragma unroll
    for (int j = 0; j < 6; ++j) bl[j] = (float)((lane >> (5 - j)) & 1);

    float bprev[NQ];
#pragma unroll
    for (int i = 0; i < NQ; ++i) bprev[i] = 0.f;
    float kk = 0.f;   // pair-diag coefficient from previous step

    // merged diagonal: phi[r] = HL[r] + kcur*ps[r], rotate state by e^{i*phi}
    auto apply_diag = [&](const float* v, float kcur) {
        float sv = 0.f;
#pragma unroll
        for (int i = 0; i < NQ; ++i) sv += v[i];
        float wl = 0.f;
#pragma unroll
        for (int j = 0; j < 6; ++j) wl = fmaf(bl[j], v[4 + j], wl);
        const float m = fmaf(-0.5f, sv, wl);
        // r bit3<->v0, bit2<->v1, bit1<->v2, bit0<->v3
        const float Hm[4] = {m, m + v[1], m + v[0], m + v[0] + v[1]};
        const float L[4]  = {0.f, v[3], v[2], v[2] + v[3]};
        float HL[NR];
#pragma unroll
        for (int r = 0; r < NR; ++r) HL[r] = Hm[r >> 2] + L[r & 3];
#pragma unroll
        for (int r = 0; r < NR; ++r) {
            const float phi = fmaf(kcur, ps[r], HL[r]);
            const float sp = __sinf(phi);
            const float cp = __cosf(phi);
            const float xr = Sr[r], xi = Si[r];
            Sr[r] = cp * xr - sp * xi;
            Si[r] = sp * xr + cp * xi;
        }
    };

    for (int tt = 0; tt < TS; ++tt) {
        // ---- prefetch NEXT step's uniform phis first (hidden under this step) ----
        float nxt[30];
        if (tt + 1 < TS) {
#pragma unroll
            for (int j = 0; j < 30; ++j) nxt[j] = ph[30 * (tt + 1) + j];
        }

        // boundary diagonal: v = a(t) + b(t-1), pair term from step t-1
        float v[NQ];
#pragma unroll
        for (int i = 0; i < NQ; ++i) v[i] = phs[i] + bprev[i];
        apply_diag(v, kk);

        // Ry block: c=cos(th/2), s=sin(th/2)
        float rc[NQ], rs[NQ];
#pragma unroll
        for (int i = 0; i < NQ; ++i) {
            const float h = 0.5f * phs[10 + i];
            rs[i] = __sinf(h);
            rc[i] = __cosf(h);
        }

        ry_r<3>(Sr, Si, rc[0], rs[0]);                    // qubit 0 (idx bit 9)
        ry_r<2>(Sr, Si, rc[1], rs[1]);                    // qubit 1 (bit 8)
        ry_r<1>(Sr, Si, rc[2], rs[2]);                    // qubit 2 (bit 7)
        ry_r<0>(Sr, Si, rc[3], rs[3]);                    // qubit 3 (bit 6)
        ry_lane<32>(lane, bp32, Sr, Si, rc[4], rs[4]);    // qubit 4 (bperm)
        ry_lane<16>(lane, bp16, Sr, Si, rc[5], rs[5]);    // qubit 5 (bperm)
        ry_lane< 8>(lane, 0,    Sr, Si, rc[6], rs[6]);    // qubit 6 (DPP)
        ry_lane< 4>(lane, 0,    Sr, Si, rc[7], rs[7]);    // qubit 7 (DPP)
        ry_lane< 2>(lane, 0,    Sr, Si, rc[8], rs[8]);    // qubit 8 (DPP)
        ry_lane< 1>(lane, 0,    Sr, Si, rc[9], rs[9]);    // qubit 9 (DPP)

#pragma unroll
        for (int i = 0; i < NQ; ++i) bprev[i] = phs[20 + i];
        kk = gk[tt];

        if (tt + 1 < TS) {
#pragma unroll
            for (int j = 0; j < 30; ++j) phs[j] = nxt[j];
        }
    }

    // trailing diagonal: b(9) phases + pairsum(9)
    apply_diag(bprev, kk);

    float* outr = out + sample * DIM;
    float* outi = out + ND * DIM + sample * DIM;
#pragma unroll
    for (int r = 0; r < NR; ++r) {
        outr[r * 64 + lane] = Sr[r];
        outi[r * 64 + lane] = Si[r];
    }
}

extern "C" void kernel_launch(void* const* d_in, const int* in_sizes, int n_in,
                              void* d_out, int out_size, void* d_ws, size_t ws_size,
                              hipStream_t stream) {
    const float* re_in = (const float*)d_in[0];
    const float* im_in = (const float*)d_in[1];
    const float* phis  = (const float*)d_in[2];
    const float* gs    = (const float*)d_in[3];
    float* out = (float*)d_out;
    qsim_kernel<<<ND, 64, 0, stream>>>(re_in, im_in, phis, gs, out);
}

// Round 13
// 80.104 us; speedup vs baseline: 1.1805x; 1.1805x over previous
//
#include <hip/hip_runtime.h>

#define NQ 10
#define TS 10
#define DIM 1024
#define ND 1024

typedef _Float16 h4 __attribute__((ext_vector_type(4)));
typedef float f4 __attribute__((ext_vector_type(4)));

// D = A*B + C, 16x16x16 f16 -> f32. Layout facts used (C/D verified m89):
//   C/D: element (row,col) at lane = col + 16*(row>>2), reg = row&3
//   A:   element (m,k)     at lane = m  + 16*(k>>2),  slot = k&3
//   B:   element (k,n)     at lane = n  + 16*(k>>2),  slot = k&3
// => a stored C-tile read as A gives its TRANSPOSE; read as B gives itself.
__device__ __forceinline__ f4 mfma16(h4 a, h4 b, f4 c) {
    return __builtin_amdgcn_mfma_f32_16x16x16f16(a, b, c, 0, 0, 0);
}
__device__ __forceinline__ h4 cvt_h4(f4 x) {
    h4 r;
    r[0] = (_Float16)x[0]; r[1] = (_Float16)x[1];
    r[2] = (_Float16)x[2]; r[3] = (_Float16)x[3];
    return r;
}
// Givens entry h[ob][ib]: diag=c, h[1][0]=s, h[0][1]=-s
__device__ __forceinline__ float hsel(int ob, int ib, float cq, float sq) {
    return (ob == ib) ? cq : (ob ? sq : -sq);
}

// One wave per sample. State P[r][l'] (16x64, r=idx>>6, l'=idx&63) kept
// permanently in MFMA C/D layout as 4 col-tiles (tile n = cols 16n..16n+15):
// lane holds (r = 4*quad + s, l' = 16n + cc), slot s, cc = lane&15.
// Step (R9-verified algebra): boundary diagonal (elementwise), then the
// Ry-block P' = G·P·H^T done as 2 MFMA stages:
//   stage G: T_n = mfma(A=P_n, B=G_st)       (rows l'_in, cols r')
//   stage H: P'_n = sum_j mfma(A=T_j, B=H_st[n][j])
__global__ __launch_bounds__(64, 1) void qsim_kernel(
    const float* __restrict__ re_in, const float* __restrict__ im_in,
    const float* __restrict__ phis, const float* __restrict__ gs,
    float* __restrict__ out)
{
    const int sample = blockIdx.x;
    const int lane = threadIdx.x;
    const int quad = lane >> 4;
    const int cc = lane & 15;
    const int c3 = (cc >> 3) & 1, c2 = (cc >> 2) & 1, c1 = (cc >> 1) & 1, c0 = cc & 1;
    const int q1 = quad >> 1, q0 = quad & 1;

    const float* pr_in = re_in + sample * DIM;
    const float* pi_in = im_in + sample * DIM;
    const float* ph = phis + sample * (3 * NQ * TS);
    const float* gsp = gs + sample * TS;

    // ---- load state into fragment layout ----
    f4 Sr[4], Si[4];
    const int lbase = 256 * quad + cc;   // r=4*quad+s -> +64*s ; l'=16n+cc -> +16n
#pragma unroll
    for (int n = 0; n < 4; ++n)
#pragma unroll
        for (int s = 0; s < 4; ++s) {
            Sr[n][s] = pr_in[lbase + 64 * s + 16 * n];
            Si[n][s] = pi_in[lbase + 64 * s + 16 * n];
        }

    const float inv = 0.15811388300841897f;  // 1/(2*sqrt(10))
    float gk[TS];
#pragma unroll
    for (int t = 0; t < TS; ++t) gk[t] = -0.5f * (gsp[t] * inv);

    // ---- normalize ----
    float nrm = 0.f;
#pragma unroll
    for (int n = 0; n < 4; ++n)
#pragma unroll
        for (int s = 0; s < 4; ++s) nrm += Sr[n][s] * Sr[n][s] + Si[n][s] * Si[n][s];
#pragma unroll
    for (int off = 32; off >= 1; off >>= 1) nrm += __shfl_xor(nrm, off, 64);
    const float scl = rsqrtf(nrm);
#pragma unroll
    for (int n = 0; n < 4; ++n) { Sr[n] *= scl; Si[n] *= scl; }

    // ---- static pairsum per element (n,s): idx = (4q+s)*64 + 16n + cc ----
    float psv[4][4];
    const int pbase = __popc(quad) + __popc(cc);
#pragma unroll
    for (int n = 0; n < 4; ++n)
#pragma unroll
        for (int s = 0; s < 4; ++s) {
            const int p = pbase + __popc(n) + __popc(s);
            const int z = NQ - 2 * p;
            psv[n][s] = 0.5f * (float)(z * z - NQ);
        }
    const float fq1 = (float)q1, fq0 = (float)q0;
    const float fc3 = (float)c3, fc2 = (float)c2, fc1 = (float)c1, fc0 = (float)c0;

    float bprev[NQ];
#pragma unroll
    for (int i = 0; i < NQ; ++i) bprev[i] = 0.f;
    float kk = 0.f;

    // qubit->bit map: r bit3=q0(quad>>1), bit2=q1(quad&1), bit1=q2(s>>1), bit0=q3(s&1)
    //                 l' bit5=q4(n>>1), bit4=q5(n&1), bit3..0=q6..q9 (cc bits)
    auto apply_diag = [&](const float* v, float kcur) {
        float sv = 0.f;
#pragma unroll
        for (int i = 0; i < NQ; ++i) sv += v[i];
        float base = fmaf(-0.5f, sv, 0.f);
        base = fmaf(fq1, v[0], base); base = fmaf(fq0, v[1], base);
        base = fmaf(fc3, v[6], base); base = fmaf(fc2, v[7], base);
        base = fmaf(fc1, v[8], base); base = fmaf(fc0, v[9], base);
        const float addS[4] = {0.f, v[3], v[2], v[2] + v[3]};
        const float addN[4] = {0.f, v[5], v[4], v[4] + v[5]};
#pragma unroll
        for (int n = 0; n < 4; ++n)
#pragma unroll
            for (int s = 0; s < 4; ++s) {
                const float phi = fmaf(kcur, psv[n][s], base + addN[n] + addS[s]);
                const float sp = __sinf(phi);
                const float cp = __cosf(phi);
                const float xr = Sr[n][s], xi = Si[n][s];
                Sr[n][s] = cp * xr - sp * xi;
                Si[n][s] = sp * xr + cp * xi;
            }
    };

    const f4 zf4 = {0.f, 0.f, 0.f, 0.f};

    for (int tt = 0; tt < TS; ++tt) {
        float phs[30];
#pragma unroll
        for (int j = 0; j < 30; ++j) phs[j] = ph[30 * tt + j];

        // boundary diagonal
        float v[NQ];
#pragma unroll
        for (int i = 0; i < NQ; ++i) v[i] = phs[i] + bprev[i];
        apply_diag(v, kk);

        // Givens coefficients for the 10 Ry's
        float C[NQ], S[NQ];
#pragma unroll
        for (int g = 0; g < NQ; ++g) {
            const float h = 0.5f * phs[10 + g];
            S[g] = __sinf(h);
            C[g] = __cosf(h);
        }

        // ---- build G_st (B-operand): G_st[r][r'] = G[r'][r] ----
        // out-bits from cc (r'), in-bits from (quad,s) (r)
        h4 gb;
        {
            const float f01 = hsel(c3, q1, C[0], S[0]) * hsel(c2, q0, C[1], S[1]);
#pragma unroll
            for (int s = 0; s < 4; ++s) {
                const float e = f01 * hsel(c1, s >> 1, C[2], S[2])
                                    * hsel(c0, s & 1,  C[3], S[3]);
                gb[s] = (_Float16)e;
            }
        }

        // ---- build H_st[n][j] (B-operand): H_st[l][l'] = H[l'][l] ----
        // l' = 16n + cc (out side), l = 16j + 4*quad + s (in side)
        h4 hb[4][4];
        {
            const float F67 = hsel(c3, q1, C[6], S[6]) * hsel(c2, q0, C[7], S[7]);
            float F89[4];
#pragma unroll
            for (int s = 0; s < 4; ++s)
                F89[s] = F67 * hsel(c1, s >> 1, C[8], S[8])
                             * hsel(c0, s & 1,  C[9], S[9]);
#pragma unroll
            for (int n = 0; n < 4; ++n)
#pragma unroll
                for (int j = 0; j < 4; ++j) {
                    const float F45 = hsel(n >> 1, j >> 1, C[4], S[4])
                                    * hsel(n & 1,  j & 1,  C[5], S[5]);
#pragma unroll
                    for (int s = 0; s < 4; ++s)
                        hb[n][j][s] = (_Float16)(F45 * F89[s]);
                }
        }

        // ---- stage G: T_n = mfma(A=P_n, B=G_st)  (rows=l'_in, cols=r') ----
        h4 ar[4], ai[4];
#pragma unroll
        for (int n = 0; n < 4; ++n) { ar[n] = cvt_h4(Sr[n]); ai[n] = cvt_h4(Si[n]); }
        f4 Tr[4], Ti[4];
#pragma unroll
        for (int n = 0; n < 4; ++n) {
            Tr[n] = mfma16(ar[n], gb, zf4);
            Ti[n] = mfma16(ai[n], gb, zf4);
        }
        h4 tr[4], ti[4];
#pragma unroll
        for (int n = 0; n < 4; ++n) { tr[n] = cvt_h4(Tr[n]); ti[n] = cvt_h4(Ti[n]); }

        // ---- stage H: P'_n = sum_j mfma(A=T_j, B=H_st[n][j]) ----
#pragma unroll
        for (int n = 0; n < 4; ++n) {
            f4 accr = zf4, acci = zf4;
#pragma unroll
            for (int j = 0; j < 4; ++j) {
                accr = mfma16(tr[j], hb[n][j], accr);
                acci = mfma16(ti[j], hb[n][j], acci);
            }
            Sr[n] = accr;
            Si[n] = acci;
        }

#pragma unroll
        for (int i = 0; i < NQ; ++i) bprev[i] = phs[20 + i];
        kk = gk[tt];
    }

    // trailing diagonal
    apply_diag(bprev, kk);

    float* outr = out + sample * DIM;
    float* outi = out + ND * DIM + sample * DIM;
#pragma unroll
    for (int n = 0; n < 4; ++n)
#pragma unroll
        for (int s = 0; s < 4; ++s) {
            outr[lbase + 64 * s + 16 * n] = Sr[n][s];
            outi[lbase + 64 * s + 16 * n] = Si[n][s];
        }
}

extern "C" void kernel_launch(void* const* d_in, const int* in_sizes, int n_in,
                              void* d_out, int out_size, void* d_ws, size_t ws_size,
                              hipStream_t stream) {
    const float* re_in = (const float*)d_in[0];
    const float* im_in = (const float*)d_in[1];
    const float* phis  = (const float*)d_in[2];
    const float* gs    = (const float*)d_in[3];
    float* out = (float*)d_out;
    qsim_kernel<<<ND, 64, 0, stream>>>(re_in, im_in, phis, gs, out);
}

// Round 15
// 80.025 us; speedup vs baseline: 1.1817x; 1.0010x over previous
//
#include <hip/hip_runtime.h>

#define NQ 10
#define TS 10
#define DIM 1024
#define ND 1024

typedef _Float16 h4 __attribute__((ext_vector_type(4)));
typedef __fp16  p2 __attribute__((ext_vector_type(2)));   // cvt_pkrtz result type
typedef float f4 __attribute__((ext_vector_type(4)));

// D = A*B + C, 16x16x16 f16 -> f32 (layout facts verified in R12):
//   C/D: (row,col) at lane = col + 16*(row>>2), reg = row&3
//   A:   (m,k)     at lane = m  + 16*(k>>2),   slot = k&3
//   B:   (k,n)     at lane = n  + 16*(k>>2),   slot = k&3
// => a stored C-tile read as A gives its TRANSPOSE; read as B gives itself.
__device__ __forceinline__ f4 mfma16(h4 a, h4 b, f4 c) {
    return __builtin_amdgcn_mfma_f32_16x16x16f16(a, b, c, 0, 0, 0);
}
__device__ __forceinline__ h4 cvt_h4(f4 x) {   // packed f32->f16 (2 insts)
    p2 lo = __builtin_amdgcn_cvt_pkrtz(x[0], x[1]);
    p2 hi = __builtin_amdgcn_cvt_pkrtz(x[2], x[3]);
    h4 r; r[0] = lo[0]; r[1] = lo[1]; r[2] = hi[0]; r[3] = hi[1];
    return r;
}
// Givens entry h[ob][ib]: diag=c, h[1][0]=s, h[0][1]=-s
__device__ __forceinline__ float hsel(int ob, int ib, float cq, float sq) {
    return (ob == ib) ? cq : (ob ? sq : -sq);
}

// One wave per sample. State P[r][l'] (16x64) in MFMA C/D layout as 4
// col-tiles. Software-pipelined: step t computes step t+1's trig (gate C/S +
// diagonal sin/cos — all state-independent) and gb/hb tiles, so they hide in
// step t's MFMA latency shadow; top-of-step diagonal is a pure FMA rotate.
__global__ __launch_bounds__(64, 1) void qsim_kernel(
    const float* __restrict__ re_in, const float* __restrict__ im_in,
    const float* __restrict__ phis, const float* __restrict__ gs,
    float* __restrict__ out)
{
    const int sample = blockIdx.x;
    const int lane = threadIdx.x;
    const int quad = lane >> 4;
    const int cc = lane & 15;
    const int c3 = (cc >> 3) & 1, c2 = (cc >> 2) & 1, c1 = (cc >> 1) & 1, c0 = cc & 1;
    const int q1 = quad >> 1, q0 = quad & 1;

    const float* pr_in = re_in + sample * DIM;
    const float* pi_in = im_in + sample * DIM;
    const float* ph = phis + sample * (3 * NQ * TS);
    const float* gsp = gs + sample * TS;

    // ---- load state into fragment layout ----
    f4 Sr[4], Si[4];
    const int lbase = 256 * quad + cc;
#pragma unroll
    for (int n = 0; n < 4; ++n)
#pragma unroll
        for (int s = 0; s < 4; ++s) {
            Sr[n][s] = pr_in[lbase + 64 * s + 16 * n];
            Si[n][s] = pi_in[lbase + 64 * s + 16 * n];
        }

    const float inv = 0.15811388300841897f;  // 1/(2*sqrt(10))
    float gk[TS];
#pragma unroll
    for (int t = 0; t < TS; ++t) gk[t] = -0.5f * (gsp[t] * inv);

    // ---- normalize ----
    float nrm = 0.f;
#pragma unroll
    for (int n = 0; n < 4; ++n)
#pragma unroll
        for (int s = 0; s < 4; ++s) nrm += Sr[n][s] * Sr[n][s] + Si[n][s] * Si[n][s];
#pragma unroll
    for (int off = 32; off >= 1; off >>= 1) nrm += __shfl_xor(nrm, off, 64);
    const float scl = rsqrtf(nrm);
#pragma unroll
    for (int n = 0; n < 4; ++n) { Sr[n] *= scl; Si[n] *= scl; }

    // ---- static pairsum per element ----
    float psv[4][4];
    const int pbase = __popc(quad) + __popc(cc);
#pragma unroll
    for (int n = 0; n < 4; ++n)
#pragma unroll
        for (int s = 0; s < 4; ++s) {
            const int p = pbase + __popc(n) + __popc(s);
            const int z = NQ - 2 * p;
            psv[n][s] = 0.5f * (float)(z * z - NQ);
        }
    const float fq1 = (float)q1, fq0 = (float)q0;
    const float fc3 = (float)c3, fc2 = (float)c2, fc1 = (float)c1, fc0 = (float)c0;

    // ---- pipelined registers: diag trig, gate tiles, b-phases ----
    float DCP[4][4], DSP[4][4];
    h4 gb; h4 hb[4][4];
    float bcur[NQ];

    // diag-trig compute (state-independent) -> (dcp, dsp)
    auto make_trig = [&](const float* v, float kcur, float dcp[4][4], float dsp[4][4]) {
        float sv = 0.f;
#pragma unroll
        for (int i = 0; i < NQ; ++i) sv += v[i];
        float base = fmaf(-0.5f, sv, 0.f);
        base = fmaf(fq1, v[0], base); base = fmaf(fq0, v[1], base);
        base = fmaf(fc3, v[6], base); base = fmaf(fc2, v[7], base);
        base = fmaf(fc1, v[8], base); base = fmaf(fc0, v[9], base);
        const float addS[4] = {0.f, v[3], v[2], v[2] + v[3]};
        const float addN[4] = {0.f, v[5], v[4], v[4] + v[5]};
#pragma unroll
        for (int n = 0; n < 4; ++n)
#pragma unroll
            for (int s = 0; s < 4; ++s) {
                const float phi = fmaf(kcur, psv[n][s], base + addN[n] + addS[s]);
                dcp[n][s] = __cosf(phi);
                dsp[n][s] = __sinf(phi);
            }
    };
    // build gate tiles from th_src (10 half-angles)
    auto make_tiles = [&](const float* th_src, h4& gbo, h4 hbo[4][4]) {
        float C[NQ], S[NQ];
#pragma unroll
        for (int g = 0; g < NQ; ++g) {
            const float h = 0.5f * th_src[g];
            S[g] = __sinf(h);
            C[g] = __cosf(h);
        }
        {
            const float f01 = hsel(c3, q1, C[0], S[0]) * hsel(c2, q0, C[1], S[1]);
            float e[4];
#pragma unroll
            for (int s = 0; s < 4; ++s)
                e[s] = f01 * hsel(c1, s >> 1, C[2], S[2]) * hsel(c0, s & 1, C[3], S[3]);
            p2 lo = __builtin_amdgcn_cvt_pkrtz(e[0], e[1]);
            p2 hi = __builtin_amdgcn_cvt_pkrtz(e[2], e[3]);
            gbo[0] = lo[0]; gbo[1] = lo[1]; gbo[2] = hi[0]; gbo[3] = hi[1];
        }
        const float F67 = hsel(c3, q1, C[6], S[6]) * hsel(c2, q0, C[7], S[7]);
        float F89[4];
#pragma unroll
        for (int s = 0; s < 4; ++s)
            F89[s] = F67 * hsel(c1, s >> 1, C[8], S[8]) * hsel(c0, s & 1, C[9], S[9]);
#pragma unroll
        for (int n = 0; n < 4; ++n)
#pragma unroll
            for (int j = 0; j < 4; ++j) {
                const float F45 = hsel(n >> 1, j >> 1, C[4], S[4])
                                * hsel(n & 1,  j & 1,  C[5], S[5]);
                p2 lo = __builtin_amdgcn_cvt_pkrtz(F45 * F89[0], F45 * F89[1]);
                p2 hi = __builtin_amdgcn_cvt_pkrtz(F45 * F89[2], F45 * F89[3]);
                hbo[n][j][0] = lo[0]; hbo[n][j][1] = lo[1];
                hbo[n][j][2] = hi[0]; hbo[n][j][3] = hi[1];
            }
    };

    // ---- prologue: step-0 tiles and boundary-0 trig ----
    {
        float phs[30];
#pragma unroll
        for (int j = 0; j < 30; ++j) phs[j] = ph[j];
        make_trig(&phs[0], 0.f, DCP, DSP);     // v0 = a0 (bprev=0), k=0
        make_tiles(&phs[10], gb, hb);
#pragma unroll
        for (int i = 0; i < NQ; ++i) bcur[i] = phs[20 + i];
    }

    const f4 zf4 = {0.f, 0.f, 0.f, 0.f};

    for (int tt = 0; tt < TS; ++tt) {
        // ---- 1. apply boundary diagonal (precomputed trig; pure FMA) ----
#pragma unroll
        for (int n = 0; n < 4; ++n)
#pragma unroll
            for (int s = 0; s < 4; ++s) {
                const float cp = DCP[n][s], sp = DSP[n][s];
                const float xr = Sr[n][s], xi = Si[n][s];
                Sr[n][s] = cp * xr - sp * xi;
                Si[n][s] = sp * xr + cp * xi;
            }

        // ---- 2. prep step tt+1 (state-independent; hides under MFMAs) ----
        h4 gbN; h4 hbN[4][4];
        float DCPn[4][4], DSPn[4][4];
        float bnext[NQ];
        const bool last = (tt == TS - 1);
        {
            float phsN[30];
            if (!last) {
#pragma unroll
                for (int j = 0; j < 30; ++j) phsN[j] = ph[30 * (tt + 1) + j];
            } else {
#pragma unroll
                for (int j = 0; j < 30; ++j) phsN[j] = 0.f;
            }
            float vN[NQ];
#pragma unroll
            for (int i = 0; i < NQ; ++i) vN[i] = phsN[i] + bcur[i];
            make_trig(vN, gk[tt], DCPn, DSPn);
            if (!last) {
                make_tiles(&phsN[10], gbN, hbN);
#pragma unroll
                for (int i = 0; i < NQ; ++i) bnext[i] = phsN[20 + i];
            }
        }

        // ---- 3. Ry block: stage G then stage H (current gb/hb) ----
        h4 ar[4], ai[4];
#pragma unroll
        for (int n = 0; n < 4; ++n) { ar[n] = cvt_h4(Sr[n]); ai[n] = cvt_h4(Si[n]); }
        f4 Tr[4], Ti[4];
#pragma unroll
        for (int n = 0; n < 4; ++n) {
            Tr[n] = mfma16(ar[n], gb, zf4);
            Ti[n] = mfma16(ai[n], gb, zf4);
        }
        h4 tr[4], ti[4];
#pragma unroll
        for (int n = 0; n < 4; ++n) { tr[n] = cvt_h4(Tr[n]); ti[n] = cvt_h4(Ti[n]); }
#pragma unroll
        for (int n = 0; n < 4; ++n) {
            f4 accr = zf4, acci = zf4;
#pragma unroll
            for (int j = 0; j < 4; ++j) {
                accr = mfma16(tr[j], hb[n][j], accr);
                acci = mfma16(ti[j], hb[n][j], acci);
            }
            Sr[n] = accr;
            Si[n] = acci;
        }

        // ---- 4. commit pipelined values ----
#pragma unroll
        for (int n = 0; n < 4; ++n)
#pragma unroll
            for (int s = 0; s < 4; ++s) { DCP[n][s] = DCPn[n][s]; DSP[n][s] = DSPn[n][s]; }
        if (!last) {
            gb = gbN;
#pragma unroll
            for (int n = 0; n < 4; ++n)
#pragma unroll
                for (int j = 0; j < 4; ++j) hb[n][j] = hbN[n][j];
#pragma unroll
            for (int i = 0; i < NQ; ++i) bcur[i] = bnext[i];
        }
    }

    // ---- trailing diagonal (trig computed during step 9) ----
#pragma unroll
    for (int n = 0; n < 4; ++n)
#pragma unroll
        for (int s = 0; s < 4; ++s) {
            const float cp = DCP[n][s], sp = DSP[n][s];
            const float xr = Sr[n][s], xi = Si[n][s];
            Sr[n][s] = cp * xr - sp * xi;
            Si[n][s] = sp * xr + cp * xi;
        }

    float* outr = out + sample * DIM;
    float* outi = out + ND * DIM + sample * DIM;
#pragma unroll
    for (int n = 0; n < 4; ++n)
#pragma unroll
        for (int s = 0; s < 4; ++s) {
            outr[lbase + 64 * s + 16 * n] = Sr[n][s];
            outi[lbase + 64 * s + 16 * n] = Si[n][s];
        }
}

extern "C" void kernel_launch(void* const* d_in, const int* in_sizes, int n_in,
                              void* d_out, int out_size, void* d_ws, size_t ws_size,
                              hipStream_t stream) {
    const float* re_in = (const float*)d_in[0];
    const float* im_in = (const float*)d_in[1];
    const float* phis  = (const float*)d_in[2];
    const float* gs    = (const float*)d_in[3];
    float* out = (float*)d_out;
    qsim_kernel<<<ND, 64, 0, stream>>>(re_in, im_in, phis, gs, out);
}

// Round 16
// 77.895 us; speedup vs baseline: 1.2140x; 1.0273x over previous
//
#include <hip/hip_runtime.h>

#define NQ 10
#define TS 10
#define DIM 1024
#define ND 1024

typedef _Float16 h4 __attribute__((ext_vector_type(4)));
typedef __fp16  p2 __attribute__((ext_vector_type(2)));   // cvt_pkrtz result type
typedef float f4 __attribute__((ext_vector_type(4)));

// D = A*B + C, 16x16x16 f16 -> f32 (layout facts verified in R12):
//   C/D: (row,col) at lane = col + 16*(row>>2), reg = row&3
//   A:   (m,k)     at lane = m  + 16*(k>>2),   slot = k&3
//   B:   (k,n)     at lane = n  + 16*(k>>2),   slot = k&3
// => a stored C-tile read as A gives its TRANSPOSE; read as B gives itself.
__device__ __forceinline__ f4 mfma16(h4 a, h4 b, f4 c) {
    return __builtin_amdgcn_mfma_f32_16x16x16f16(a, b, c, 0, 0, 0);
}
__device__ __forceinline__ h4 cvt_h4(f4 x) {
    p2 lo = __builtin_amdgcn_cvt_pkrtz(x[0], x[1]);
    p2 hi = __builtin_amdgcn_cvt_pkrtz(x[2], x[3]);
    h4 r; r[0] = lo[0]; r[1] = lo[1]; r[2] = hi[0]; r[3] = hi[1];
    return r;
}
// Givens entry h[ob][ib]: diag=c, h[1][0]=s, h[0][1]=-s
__device__ __forceinline__ float hsel(int ob, int ib, float cq, float sq) {
    return (ob == ib) ? cq : (ob ? sq : -sq);
}

// One wave per sample. State P[r][l'] (16x64) in MFMA C/D layout as 4
// col-tiles. R15: fully-unrolled t-loop + 1.5-step software pipeline on the
// uniform phi loads: iter t ISSUES loads for step t+2 (top) and CONSUMES
// step t+1's phis (bottom, after the MFMA block) — the s_waitcnt for each
// load retires a full iteration (~thousands of cycles) before use.
__global__ __launch_bounds__(64, 1) void qsim_kernel(
    const float* __restrict__ re_in, const float* __restrict__ im_in,
    const float* __restrict__ phis, const float* __restrict__ gs,
    float* __restrict__ out)
{
    const int sample = blockIdx.x;
    const int lane = threadIdx.x;
    const int quad = lane >> 4;
    const int cc = lane & 15;
    const int c3 = (cc >> 3) & 1, c2 = (cc >> 2) & 1, c1 = (cc >> 1) & 1, c0 = cc & 1;
    const int q1 = quad >> 1, q0 = quad & 1;

    const float* pr_in = re_in + sample * DIM;
    const float* pi_in = im_in + sample * DIM;
    const float* ph = phis + sample * (3 * NQ * TS);
    const float* gsp = gs + sample * TS;

    // ---- load state into fragment layout ----
    f4 Sr[4], Si[4];
    const int lbase = 256 * quad + cc;
#pragma unroll
    for (int n = 0; n < 4; ++n)
#pragma unroll
        for (int s = 0; s < 4; ++s) {
            Sr[n][s] = pr_in[lbase + 64 * s + 16 * n];
            Si[n][s] = pi_in[lbase + 64 * s + 16 * n];
        }

    const float inv = 0.15811388300841897f;  // 1/(2*sqrt(10))
    float gk[TS];
#pragma unroll
    for (int t = 0; t < TS; ++t) gk[t] = -0.5f * (gsp[t] * inv);

    // ---- normalize ----
    float nrm = 0.f;
#pragma unroll
    for (int n = 0; n < 4; ++n)
#pragma unroll
        for (int s = 0; s < 4; ++s) nrm += Sr[n][s] * Sr[n][s] + Si[n][s] * Si[n][s];
#pragma unroll
    for (int off = 32; off >= 1; off >>= 1) nrm += __shfl_xor(nrm, off, 64);
    const float scl = rsqrtf(nrm);
#pragma unroll
    for (int n = 0; n < 4; ++n) { Sr[n] *= scl; Si[n] *= scl; }

    // ---- static pairsum per element ----
    float psv[4][4];
    const int pbase = __popc(quad) + __popc(cc);
#pragma unroll
    for (int n = 0; n < 4; ++n)
#pragma unroll
        for (int s = 0; s < 4; ++s) {
            const int p = pbase + __popc(n) + __popc(s);
            const int z = NQ - 2 * p;
            psv[n][s] = 0.5f * (float)(z * z - NQ);
        }
    const float fq1 = (float)q1, fq0 = (float)q0;
    const float fc3 = (float)c3, fc2 = (float)c2, fc1 = (float)c1, fc0 = (float)c0;

    float DCP[4][4], DSP[4][4];
    h4 gb; h4 hb[4][4];
    float bcur[NQ];

    // diag-trig (state-independent) -> (dcp, dsp)
    auto make_trig = [&](const float* v, float kcur, float dcp[4][4], float dsp[4][4]) {
        float sv = 0.f;
#pragma unroll
        for (int i = 0; i < NQ; ++i) sv += v[i];
        float base = fmaf(-0.5f, sv, 0.f);
        base = fmaf(fq1, v[0], base); base = fmaf(fq0, v[1], base);
        base = fmaf(fc3, v[6], base); base = fmaf(fc2, v[7], base);
        base = fmaf(fc1, v[8], base); base = fmaf(fc0, v[9], base);
        const float addS[4] = {0.f, v[3], v[2], v[2] + v[3]};
        const float addN[4] = {0.f, v[5], v[4], v[4] + v[5]};
#pragma unroll
        for (int n = 0; n < 4; ++n)
#pragma unroll
            for (int s = 0; s < 4; ++s) {
                const float phi = fmaf(kcur, psv[n][s], base + addN[n] + addS[s]);
                float sp, cp;
                __sincosf(phi, &sp, &cp);
                dcp[n][s] = cp;
                dsp[n][s] = sp;
            }
    };
    // build gate tiles from th_src (10 thetas)
    auto make_tiles = [&](const float* th_src, h4& gbo, h4 hbo[4][4]) {
        float C[NQ], S[NQ];
#pragma unroll
        for (int g = 0; g < NQ; ++g) {
            float sg, cg;
            __sincosf(0.5f * th_src[g], &sg, &cg);
            S[g] = sg; C[g] = cg;
        }
        {
            const float f01 = hsel(c3, q1, C[0], S[0]) * hsel(c2, q0, C[1], S[1]);
            float e[4];
#pragma unroll
            for (int s = 0; s < 4; ++s)
                e[s] = f01 * hsel(c1, s >> 1, C[2], S[2]) * hsel(c0, s & 1, C[3], S[3]);
            p2 lo = __builtin_amdgcn_cvt_pkrtz(e[0], e[1]);
            p2 hi = __builtin_amdgcn_cvt_pkrtz(e[2], e[3]);
            gbo[0] = lo[0]; gbo[1] = lo[1]; gbo[2] = hi[0]; gbo[3] = hi[1];
        }
        const float F67 = hsel(c3, q1, C[6], S[6]) * hsel(c2, q0, C[7], S[7]);
        float F89[4];
#pragma unroll
        for (int s = 0; s < 4; ++s)
            F89[s] = F67 * hsel(c1, s >> 1, C[8], S[8]) * hsel(c0, s & 1, C[9], S[9]);
#pragma unroll
        for (int n = 0; n < 4; ++n)
#pragma unroll
            for (int j = 0; j < 4; ++j) {
                const float F45 = hsel(n >> 1, j >> 1, C[4], S[4])
                                * hsel(n & 1,  j & 1,  C[5], S[5]);
                p2 lo = __builtin_amdgcn_cvt_pkrtz(F45 * F89[0], F45 * F89[1]);
                p2 hi = __builtin_amdgcn_cvt_pkrtz(F45 * F89[2], F45 * F89[3]);
                hbo[n][j][0] = lo[0]; hbo[n][j][1] = lo[1];
                hbo[n][j][2] = hi[0]; hbo[n][j][3] = hi[1];
            }
    };

    // ---- prologue: step-0 prep (direct), then load step-1 phis into pipe[0] ----
    {
        float phs0[30];
#pragma unroll
        for (int j = 0; j < 30; ++j) phs0[j] = ph[j];
        make_trig(&phs0[0], 0.f, DCP, DSP);     // v0 = a0 (b(-1)=0), k=0
        make_tiles(&phs0[10], gb, hb);
#pragma unroll
        for (int i = 0; i < NQ; ++i) bcur[i] = phs0[20 + i];
    }
    float pipe[2][30];
#pragma unroll
    for (int j = 0; j < 30; ++j) pipe[0][j] = ph[30 + j];   // phis(step 1)

    const f4 zf4 = {0.f, 0.f, 0.f, 0.f};

#pragma unroll
    for (int tt = 0; tt < TS; ++tt) {
        // ---- 1. apply boundary diagonal (precomputed trig; pure FMA) ----
#pragma unroll
        for (int n = 0; n < 4; ++n)
#pragma unroll
            for (int s = 0; s < 4; ++s) {
                const float cp = DCP[n][s], sp = DSP[n][s];
                const float xr = Sr[n][s], xi = Si[n][s];
                Sr[n][s] = cp * xr - sp * xi;
                Si[n][s] = sp * xr + cp * xi;
            }

        // ---- 2. ISSUE loads for step tt+2 (consumed 1.5 iterations later) ----
        if (tt + 2 < TS) {
#pragma unroll
            for (int j = 0; j < 30; ++j) pipe[(tt + 1) & 1][j] = ph[30 * (tt + 2) + j];
        }

        // ---- 3. Ry block: stage G then stage H ----
        h4 ar[4], ai[4];
#pragma unroll
        for (int n = 0; n < 4; ++n) { ar[n] = cvt_h4(Sr[n]); ai[n] = cvt_h4(Si[n]); }
        f4 Tr[4], Ti[4];
#pragma unroll
        for (int n = 0; n < 4; ++n) {
            Tr[n] = mfma16(ar[n], gb, zf4);
            Ti[n] = mfma16(ai[n], gb, zf4);
        }
        h4 tr[4], ti[4];
#pragma unroll
        for (int n = 0; n < 4; ++n) { tr[n] = cvt_h4(Tr[n]); ti[n] = cvt_h4(Ti[n]); }
#pragma unroll
        for (int n = 0; n < 4; ++n) {
            f4 accr = zf4, acci = zf4;
#pragma unroll
            for (int j = 0; j < 4; ++j) {
                accr = mfma16(tr[j], hb[n][j], accr);
                acci = mfma16(ti[j], hb[n][j], acci);
            }
            Sr[n] = accr;
            Si[n] = acci;
        }

        // ---- 4. prep step tt+1 from RESIDENT phis (loaded one iter ago) ----
        if (tt + 1 < TS) {
            const float* pN = pipe[tt & 1];
            float vN[NQ];
#pragma unroll
            for (int i = 0; i < NQ; ++i) vN[i] = pN[i] + bcur[i];
            make_trig(vN, gk[tt], DCP, DSP);
            make_tiles(&pN[10], gb, hb);
#pragma unroll
            for (int i = 0; i < NQ; ++i) bcur[i] = pN[20 + i];
        } else {
            make_trig(bcur, gk[TS - 1], DCP, DSP);   // trailing diagonal
        }
    }

    // ---- trailing diagonal ----
#pragma unroll
    for (int n = 0; n < 4; ++n)
#pragma unroll
        for (int s = 0; s < 4; ++s) {
            const float cp = DCP[n][s], sp = DSP[n][s];
            const float xr = Sr[n][s], xi = Si[n][s];
            Sr[n][s] = cp * xr - sp * xi;
            Si[n][s] = sp * xr + cp * xi;
        }

    float* outr = out + sample * DIM;
    float* outi = out + ND * DIM + sample * DIM;
#pragma unroll
    for (int n = 0; n < 4; ++n)
#pragma unroll
        for (int s = 0; s < 4; ++s) {
            outr[lbase + 64 * s + 16 * n] = Sr[n][s];
            outi[lbase + 64 * s + 16 * n] = Si[n][s];
        }
}

extern "C" void kernel_launch(void* const* d_in, const int* in_sizes, int n_in,
                              void* d_out, int out_size, void* d_ws, size_t ws_size,
                              hipStream_t stream) {
    const float* re_in = (const float*)d_in[0];
    const float* im_in = (const float*)d_in[1];
    const float* phis  = (const float*)d_in[2];
    const float* gs    = (const float*)d_in[3];
    float* out = (float*)d_out;
    qsim_kernel<<<ND, 64, 0, stream>>>(re_in, im_in, phis, gs, out);
}